// Round 11
// baseline (192.901 us; speedup 1.0000x reference)
//
#include <hip/hip_runtime.h>

#define AS1 __attribute__((address_space(1)))
#define AS3 __attribute__((address_space(3)))

typedef _Float16 half_t;
typedef __attribute__((ext_vector_type(8))) _Float16 f16x8;  // 8 f16 = 4 VGPRs
typedef __attribute__((ext_vector_type(4))) float f32x4;

static constexpr int Bsz = 4096;   // batch
static constexpr int INs = 512;    // input features
static constexpr int Hs  = 1024;   // hidden
static constexpr int BM  = 128;    // batch rows per block
static constexpr int BH  = 32;     // h-cols per block (x4 gates = 128 eff cols)
static constexpr int BK2 = 32;     // K-tile (halved vs r7 to afford dbuf in 32 KB)
static constexpr int NIT2 = INs / BK2 + Hs / BK2;   // 16 + 32 = 48 K-steps

static constexpr size_t XN  = (size_t)Bsz * INs;
static constexpr size_t HXN = (size_t)Bsz * Hs;
static constexpr size_t WXN = (size_t)4 * Hs * INs;
static constexpr size_t WHN = (size_t)4 * Hs * Hs;
static constexpr size_t OFF_X  = 0;
static constexpr size_t OFF_HX = XN;
static constexpr size_t OFF_WX = XN + HXN;
static constexpr size_t OFF_WH = XN + HXN + WXN;
static constexpr size_t TOT    = XN + HXN + WXN + WHN;   // 12,582,912 f16

__device__ __forceinline__ float sigm(float x) {
  return 1.0f / (1.0f + __expf(-x));
}
__device__ __forceinline__ float tanh_fast(float x) {
  const float e = __expf(2.0f * x);
  return 1.0f - 2.0f / (e + 1.0f);
}

// fp32 -> fp16 (RNE) of the four matmul operands into ws. Loop-free;
// grid covers TOT/8 chunks exactly.
__global__ __launch_bounds__(256)
void cvt_kernel(const float* __restrict__ x, const float* __restrict__ hx,
                const float* __restrict__ wx, const float* __restrict__ wh,
                half_t* __restrict__ ws) {
  const size_t cid = (size_t)blockIdx.x * 256 + threadIdx.x;
  const size_t e = cid * 8;
  const float* src; size_t off;
  if (e < OFF_HX)      { src = x;  off = e - OFF_X; }
  else if (e < OFF_WX) { src = hx; off = e - OFF_HX; }
  else if (e < OFF_WH) { src = wx; off = e - OFF_WX; }
  else                 { src = wh; off = e - OFF_WH; }
  const f32x4 a = *(const f32x4*)(src + off);
  const f32x4 b = *(const f32x4*)(src + off + 4);
  f16x8 o;
  o[0]=(half_t)a[0]; o[1]=(half_t)a[1]; o[2]=(half_t)a[2]; o[3]=(half_t)a[3];
  o[4]=(half_t)b[0]; o[5]=(half_t)b[1]; o[6]=(half_t)b[2]; o[7]=(half_t)b[3];
  *(f16x8*)(ws + e) = o;
}

// ---------------------------------------------------------------------------
// r11: the one untested structure-matrix cell -- {2-phase dbuf, 4 blocks/CU}.
// Matrix so far: {1ph,4blk}=72us(r7) {2ph,2blk}=89(r9) {8ph,1blk}=81.5(r5).
// r9 bundled dbuf with halved occupancy; halving BK to 32 affords a full
// double buffer in the SAME 32 KB LDS -> dbuf + 4 blocks/CU simultaneously.
// Per unit work everything is identical to r7 (total MFMA, ds_read bytes,
// staging bytes, barrier count: 48x1 vs 24x2); the ONLY change: stage(t+1)
// is issued a full compute-phase before the barrier that drains it
// (r7: drain immediately after issue -> latency fully exposed each step).
//  - Staging dest = 16*tid bytes = wave-uniform + lane*16 (m104-compliant).
//  - XOR swizzle: slot (e,c2) holds global chunk c2 ^ ((e>>2)&3); read-side
//    bank pattern = 8 groups x 8 lanes, structurally identical to r7's
//    measured-0-conflict layout. Writer/reader verified element-wise.
//  - A-frag chunk for mfma 16x16x32 = grp exactly (BK=32 -> no kk loop).
//  - r7's bijective XCD swizzle + cheap epilogue retained.
// Tripwires: SQ_LDS_BANK_CONFLICT > 0 or GEMM > 78us -> revert to r7.
// ---------------------------------------------------------------------------
__global__ __launch_bounds__(256, 4)
void plstm_gemm(const half_t* __restrict__ xin,   // [B,IN]  f16
                const half_t* __restrict__ hxp,   // [B,H]   f16
                const float* __restrict__ cxp,    // [B,H]
                const half_t* __restrict__ wxh,   // [4H,IN] f16
                const float* __restrict__ biasp,  // [4H]
                const half_t* __restrict__ whh,   // [4H,H]  f16
                const float* __restrict__ timep,  // [B]
                const float* __restrict__ taup,   // [H]
                const float* __restrict__ sp,     // [H]
                const float* __restrict__ alphap, // [1]
                const float* __restrict__ rhop,   // [1]
                float* __restrict__ outp)         // [2,B,H] = hy ; cy
{
  // slot (row e, chunk c2) holds global 16B chunk c2 ^ ((e>>2)&3)
  __shared__ half_t As[2][BM * BK2];   // 2 x 8 KB
  __shared__ half_t Bs[2][BM * BK2];   // 2 x 8 KB

  const int tid  = threadIdx.x;
  const int w    = tid >> 6;
  const int lane = tid & 63;
  const int l15  = lane & 15;
  const int grp  = lane >> 4;
  const int wr   = w >> 1;
  const int wc   = w & 1;

  // XCD-locality swizzle (r7): wg = 8q+k -> bx = q>>2, by = 4k+(q&3)
  const int wg = blockIdx.x + (blockIdx.y << 5);
  const int xk = wg & 7;
  const int q  = wg >> 3;
  const int m0 = (q >> 2) * BM;
  const int h0 = ((xk << 2) + (q & 3)) * BH;

  f32x4 acc[4][4] = {};              // [m-subtile][gate]

  // staging assignment: thread -> rows {sr, 64+sr}, chunk col sc
  const int sr  = tid >> 2;          // 0..63
  const int sc  = tid & 3;           // chunk col 0..3
  const int swz = (tid >> 4) & 3;    // == (e>>2)&3 for e = i*64+sr
  const int gcA = sc ^ swz;          // global chunk this thread stages

  // stage tile t into buffer parity p. Dest half-index = i*2048 + 8*tid
  // (bytes: i*4096 + 16*tid -> wave-uniform base + lane*16).
  auto stage = [&](int t, int p) {
    const bool p1 = t >= INs / BK2;
    const half_t* Ap = p1 ? hxp : xin;
    const half_t* Wp = p1 ? whh : wxh;
    const int Ka = p1 ? Hs : INs;
    const int k0 = (p1 ? (t - INs / BK2) : t) * BK2;
    #pragma unroll
    for (int i = 0; i < 2; ++i) {
      const int e    = i * 64 + sr;
      const int wrow = ((e >> 4) & 3) * Hs + h0 + ((e >> 6) << 4) + (e & 15);
      const half_t* ga = Ap + (size_t)(m0 + e) * Ka + (k0 + gcA * 8);
      __builtin_amdgcn_global_load_lds((AS1 void*)ga,
          (AS3 void*)(As[p] + e * 32 + sc * 8), 16, 0, 0);
      const half_t* gw = Wp + (size_t)wrow * Ka + (k0 + gcA * 8);
      __builtin_amdgcn_global_load_lds((AS1 void*)gw,
          (AS3 void*)(Bs[p] + e * 32 + sc * 8), 16, 0, 0);
    }
  };

  // compute tile from buffer parity p: lane reads row l15-of-subtile,
  // global chunk grp -> slot chunk grp ^ ((e>>2)&3) = grp ^ (l15>>2).
  auto compute = [&](int p) {
    const int cs = (l15 >> 2) & 3;
    f16x8 af[4], bfr[4];
    #pragma unroll
    for (int mt = 0; mt < 4; ++mt) {
      const int e = wr * 64 + mt * 16 + l15;
      af[mt] = *(const f16x8*)(As[p] + e * 32 + ((grp ^ cs) * 8));
    }
    #pragma unroll
    for (int nt = 0; nt < 4; ++nt) {
      const int e = wc * 64 + nt * 16 + l15;
      bfr[nt] = *(const f16x8*)(Bs[p] + e * 32 + ((grp ^ cs) * 8));
    }
    #pragma unroll
    for (int mt = 0; mt < 4; ++mt)
      #pragma unroll
      for (int nt = 0; nt < 4; ++nt)
        acc[mt][nt] = __builtin_amdgcn_mfma_f32_16x16x32_f16(
            af[mt], bfr[nt], acc[mt][nt], 0, 0, 0);
  };

  // ---- prologue: tile0 -> parity 0 ----
  stage(0, 0);
  __syncthreads();

  // ---- 2-phase main loop: stage(t+1) FIRST, compute(t), ONE barrier ----
  // The barrier's vmcnt(0) drain lands a full compute-phase after the
  // stage issue; buffer (t+1)&1 was freed by the barrier ending step t-1.
  #pragma unroll 1
  for (int t = 0; t < NIT2 - 1; ++t) {
    stage(t + 1, (t + 1) & 1);
    compute(t & 1);
    __syncthreads();
  }
  compute((NIT2 - 1) & 1);   // t = 47 (parity 1), no prefetch

  // ---- fused epilogue (r7): each thread owns ONE h and 16 batch rows ----
  const int h = h0 + wc * 16 + l15;
  const float bi  = biasp[h];
  const float bfv = biasp[Hs + h];
  const float bg  = biasp[2 * Hs + h];
  const float bo  = biasp[3 * Hs + h];
  const float sv = sp[h], tauv = taup[h];
  const float alphav = alphap[0], rhov = rhop[0], rh = 0.5f * rhov;
  const float rtau   = 1.0f / tauv;    // hoisted: one divide
  const float tworho = 2.0f / rhov;    // hoisted: one divide

  #pragma unroll
  for (int mt = 0; mt < 4; ++mt) {
    const f32x4 t4 = *(const f32x4*)(timep + m0 + wr * 64 + mt * 16 + grp * 4);
    #pragma unroll
    for (int r = 0; r < 4; ++r) {
      // C/D layout (m89-verified): col = lane&15, row = grp*4 + reg
      const int brow = m0 + wr * 64 + mt * 16 + grp * 4 + r;
      // phi = fmod(tv-s, tau)/tau == q - trunc(q), q = (tv-s)/tau
      const float qv  = (t4[r] - sv) * rtau;
      const float phi = qv - truncf(qv);
      const float kv  = phi < rh   ? phi * tworho
                      : (phi < rhov ? 2.0f - phi * tworho
                                    : alphav * phi);

      const float iv = acc[mt][0][r] + bi;
      const float fv = acc[mt][1][r] + bfv;
      const float gv = acc[mt][2][r] + bg;
      const float ov = acc[mt][3][r] + bo;
      const float cxv = cxp[(size_t)brow * Hs + h];
      const float ft = sigm(fv + 1.0f - kv);
      const float it2 = sigm(iv) * kv;
      const float gt = tanh_fast(gv) * kv;
      const float ot = sigm(ov) * kv;
      const float cy = ft * cxv + it2 * gt;
      const float hy = ot * tanh_fast(cy);

      outp[(size_t)brow * Hs + h] = hy;
      outp[(size_t)Bsz * Hs + (size_t)brow * Hs + h] = cy;
    }
  }
}

// Fallback (no usable ws): single kernel, fp32 converted during staging
// (r0 structure, unchanged; BK=64 layout).
__global__ __launch_bounds__(256, 3)
void plstm_gemm_f32(const float* __restrict__ xin, const float* __restrict__ timep,
                    const float* __restrict__ hxp, const float* __restrict__ cxp,
                    const float* __restrict__ wxh, const float* __restrict__ biasp,
                    const float* __restrict__ whh, const float* __restrict__ taup,
                    const float* __restrict__ sp, const float* __restrict__ alphap,
                    const float* __restrict__ rhop, float* __restrict__ outp)
{
  __shared__ half_t As[BM * 64];
  __shared__ half_t Bsf[BM * 64];

  const int tid  = threadIdx.x;
  const int w    = tid >> 6;
  const int lane = tid & 63;
  const int l15  = lane & 15;
  const int grp  = lane >> 4;
  const int wr   = w >> 1;
  const int wc   = w & 1;

  const int m0 = blockIdx.x * BM;
  const int h0 = blockIdx.y * BH;

  f32x4 acc[4][4] = {};
  const int ldr = tid >> 3;
  const int ldc = tid & 7;
  const int NIT = INs / 64 + Hs / 64;

  for (int it = 0; it < NIT; ++it) {
    const bool p1 = it >= INs / 64;
    const float* Ap = p1 ? hxp : xin;
    const float* Wp = p1 ? whh : wxh;
    const int Ka = p1 ? Hs : INs;
    const int k0 = (p1 ? (it - INs / 64) : it) * 64;
    #pragma unroll
    for (int i = 0; i < 4; ++i) {
      const int e    = i * 32 + ldr;
      const int gc8  = ldc ^ (e & 7);
      const int wrow = ((e >> 4) & 3) * Hs + h0 + ((e >> 6) << 4) + (e & 15);
      const float* ga = Ap + (size_t)(m0 + e) * Ka + (k0 + gc8 * 8);
      const f32x4 a0v = *(const f32x4*)ga, a1v = *(const f32x4*)(ga + 4);
      f16x8 pa;
      pa[0]=(half_t)a0v[0]; pa[1]=(half_t)a0v[1]; pa[2]=(half_t)a0v[2]; pa[3]=(half_t)a0v[3];
      pa[4]=(half_t)a1v[0]; pa[5]=(half_t)a1v[1]; pa[6]=(half_t)a1v[2]; pa[7]=(half_t)a1v[3];
      *(f16x8*)(As + (e * 8 + ldc) * 8) = pa;
      const float* gw = Wp + (size_t)wrow * Ka + (k0 + gc8 * 8);
      const f32x4 b0v = *(const f32x4*)gw, b1v = *(const f32x4*)(gw + 4);
      f16x8 pb;
      pb[0]=(half_t)b0v[0]; pb[1]=(half_t)b0v[1]; pb[2]=(half_t)b0v[2]; pb[3]=(half_t)b0v[3];
      pb[4]=(half_t)b1v[0]; pb[5]=(half_t)b1v[1]; pb[6]=(half_t)b1v[2]; pb[7]=(half_t)b1v[3];
      *(f16x8*)(Bsf + (e * 8 + ldc) * 8) = pb;
    }
    __syncthreads();
    #pragma unroll
    for (int kk = 0; kk < 2; ++kk) {
      const int c8x = kk * 4 + grp;
      f16x8 af[4], bfr[4];
      #pragma unroll
      for (int mt = 0; mt < 4; ++mt) {
        const int e = wr * 64 + mt * 16 + l15;
        af[mt] = *(const f16x8*)(As + (e * 8 + (c8x ^ (l15 & 7))) * 8);
      }
      #pragma unroll
      for (int nt = 0; nt < 4; ++nt) {
        const int e = wc * 64 + nt * 16 + l15;
        bfr[nt] = *(const f16x8*)(Bsf + (e * 8 + (c8x ^ (l15 & 7))) * 8);
      }
      #pragma unroll
      for (int mt = 0; mt < 4; ++mt)
        #pragma unroll
        for (int nt = 0; nt < 4; ++nt)
          acc[mt][nt] = __builtin_amdgcn_mfma_f32_16x16x32_f16(
              af[mt], bfr[nt], acc[mt][nt], 0, 0, 0);
    }
    __syncthreads();
  }

  const int h = h0 + wc * 16 + l15;
  const float bi  = biasp[h];
  const float bfv = biasp[Hs + h];
  const float bg  = biasp[2 * Hs + h];
  const float bo  = biasp[3 * Hs + h];
  const float sv = sp[h], tauv = taup[h];
  const float alphav = alphap[0], rhov = rhop[0], rh = 0.5f * rhov;
  const float rtau   = 1.0f / tauv;
  const float tworho = 2.0f / rhov;

  #pragma unroll
  for (int mt = 0; mt < 4; ++mt) {
    const f32x4 t4 = *(const f32x4*)(timep + m0 + wr * 64 + mt * 16 + grp * 4);
    #pragma unroll
    for (int r = 0; r < 4; ++r) {
      const int brow = m0 + wr * 64 + mt * 16 + grp * 4 + r;
      const float qv  = (t4[r] - sv) * rtau;
      const float phi = qv - truncf(qv);
      const float kv  = phi < rh   ? phi * tworho
                      : (phi < rhov ? 2.0f - phi * tworho
                                    : alphav * phi);
      const float iv = acc[mt][0][r] + bi;
      const float fv = acc[mt][1][r] + bfv;
      const float gv = acc[mt][2][r] + bg;
      const float ov = acc[mt][3][r] + bo;
      const float cxv = cxp[(size_t)brow * Hs + h];
      const float ft = sigm(fv + 1.0f - kv);
      const float it2 = sigm(iv) * kv;
      const float gt = tanh_fast(gv) * kv;
      const float ot = sigm(ov) * kv;
      const float cy = ft * cxv + it2 * gt;
      const float hy = ot * tanh_fast(cy);
      outp[(size_t)brow * Hs + h] = hy;
      outp[(size_t)Bsz * Hs + (size_t)brow * Hs + h] = cy;
    }
  }
}

extern "C" void kernel_launch(void* const* d_in, const int* in_sizes, int n_in,
                              void* d_out, int out_size, void* d_ws, size_t ws_size,
                              hipStream_t stream) {
  (void)in_sizes; (void)n_in; (void)out_size;
  const float* xin   = (const float*)d_in[0];
  const float* timep = (const float*)d_in[1];
  const float* hxp   = (const float*)d_in[2];
  const float* cxp   = (const float*)d_in[3];
  const float* wxh   = (const float*)d_in[4];
  const float* biasp = (const float*)d_in[5];
  const float* whh   = (const float*)d_in[6];
  const float* taup  = (const float*)d_in[7];
  const float* sp    = (const float*)d_in[8];
  const float* alphap= (const float*)d_in[9];
  const float* rhop  = (const float*)d_in[10];
  float* outp = (float*)d_out;

  dim3 grid(Bsz / BM, Hs / BH);   // 32 x 32 = 1024 blocks = 4 per CU
  if (ws_size >= TOT * sizeof(half_t)) {
    half_t* ws = (half_t*)d_ws;
    cvt_kernel<<<(int)(TOT / 8 / 256), 256, 0, stream>>>(xin, hxp, wxh, whh, ws);
    plstm_gemm<<<grid, 256, 0, stream>>>(
        ws + OFF_X, ws + OFF_HX, cxp, ws + OFF_WX, biasp, ws + OFF_WH,
        timep, taup, sp, alphap, rhop, outp);
  } else {
    plstm_gemm_f32<<<grid, 256, 0, stream>>>(
        xin, timep, hxp, cxp, wxh, biasp, whh,
        taup, sp, alphap, rhop, outp);
  }
}

// Round 12
// 178.722 us; speedup vs baseline: 1.0793x; 1.0793x over previous
//
#include <hip/hip_runtime.h>

#define AS1 __attribute__((address_space(1)))
#define AS3 __attribute__((address_space(3)))

typedef _Float16 half_t;
typedef __attribute__((ext_vector_type(8))) _Float16 f16x8;  // 8 f16 = 4 VGPRs
typedef __attribute__((ext_vector_type(4))) float f32x4;

static constexpr int Bsz = 4096;   // batch
static constexpr int INs = 512;    // input features
static constexpr int Hs  = 1024;   // hidden
static constexpr int BM  = 128;    // batch rows per block
static constexpr int BH  = 32;     // h-cols per block (x4 gates = 128 eff cols)
static constexpr int BK  = 64;     // K-tile
static constexpr int NIT = INs / BK + Hs / BK;   // 8 + 16 = 24 K-iters

static constexpr size_t XN  = (size_t)Bsz * INs;
static constexpr size_t HXN = (size_t)Bsz * Hs;
static constexpr size_t WXN = (size_t)4 * Hs * INs;
static constexpr size_t WHN = (size_t)4 * Hs * Hs;
static constexpr size_t OFF_X  = 0;
static constexpr size_t OFF_HX = XN;
static constexpr size_t OFF_WX = XN + HXN;
static constexpr size_t OFF_WH = XN + HXN + WXN;
static constexpr size_t TOT    = XN + HXN + WXN + WHN;   // 12,582,912 f16

__device__ __forceinline__ float sigm(float x) {
  return 1.0f / (1.0f + __expf(-x));
}
__device__ __forceinline__ float tanh_fast(float x) {
  const float e = __expf(2.0f * x);
  return 1.0f - 2.0f / (e + 1.0f);
}

// fp32 -> fp16 (RNE) of the four matmul operands into ws. Loop-free;
// grid covers TOT/8 chunks exactly.
__global__ __launch_bounds__(256)
void cvt_kernel(const float* __restrict__ x, const float* __restrict__ hx,
                const float* __restrict__ wx, const float* __restrict__ wh,
                half_t* __restrict__ ws) {
  const size_t cid = (size_t)blockIdx.x * 256 + threadIdx.x;
  const size_t e = cid * 8;
  const float* src; size_t off;
  if (e < OFF_HX)      { src = x;  off = e - OFF_X; }
  else if (e < OFF_WX) { src = hx; off = e - OFF_HX; }
  else if (e < OFF_WH) { src = wx; off = e - OFF_WX; }
  else                 { src = wh; off = e - OFF_WH; }
  const f32x4 a = *(const f32x4*)(src + off);
  const f32x4 b = *(const f32x4*)(src + off + 4);
  f16x8 o;
  o[0]=(half_t)a[0]; o[1]=(half_t)a[1]; o[2]=(half_t)a[2]; o[3]=(half_t)a[3];
  o[4]=(half_t)b[0]; o[5]=(half_t)b[1]; o[6]=(half_t)b[2]; o[7]=(half_t)b[3];
  *(f16x8*)(ws + e) = o;
}

// ---------------------------------------------------------------------------
// FINAL (r7; measured 71.0-72.1 us GEMM, 178.6-182.4 us total across two
// independent benches; session best).
// Structure: 128x128 tile, 1-phase K-loop, 4 blocks/CU co-resident (32 KB
// LDS, 64 VGPR) -- implicit cross-block wave overlap (m114) fills barrier
// stalls. Complete session structure matrix (r1-r11):
//   {1ph,4blk}=72us BEST | {2ph,2blk}=89 (r9: occupancy loss) |
//   {2ph,4blk,BK32}=83.5 w/ 6.3M bank conflicts; conflict-corrected
//   projection ~73.5 = neutral (r11) | {8ph,1blk}=81.5 (r5: lockstep) |
//   A-in-registers x3 = compiler sinks/remats prefetch (r4/r6/r8).
// On this short-K latency-dominated shape, TLP at 4 blocks/CU beats every
// explicit pipeline expressible at HIP source level.
// Deltas over the original baseline:
//  1. Bijective XCD swizzle (wg = 8q+k -> bx = q>>2, by = 4k+(q&3)):
//     each XCD's co-resident blocks share 4 weight panels = 1.5 MB ->
//     L2-resident staging (was L3-latency streaming). -9.5 us measured.
//  2. Cheap epilogue: hoisted rtau=1/tau, tworho=2/rho; phi = q - trunc(q)
//     (== fmod(t-s,tau)/tau in exact arithmetic); vectorized time loads.
// XOR-swizzled LDS chunk layout: 0 measured bank conflicts.
// Eff-col c -> gate (c>>4)&3, h = h0 + (c>>6)*16 + (c&15): all four gates
// of one (b,h) sit in the same lane across acc[mt][0..3].
// ---------------------------------------------------------------------------
__global__ __launch_bounds__(256, 4)
void plstm_gemm(const half_t* __restrict__ xin,   // [B,IN]  f16
                const half_t* __restrict__ hxp,   // [B,H]   f16
                const float* __restrict__ cxp,    // [B,H]
                const half_t* __restrict__ wxh,   // [4H,IN] f16
                const float* __restrict__ biasp,  // [4H]
                const half_t* __restrict__ whh,   // [4H,H]  f16
                const float* __restrict__ timep,  // [B]
                const float* __restrict__ taup,   // [H]
                const float* __restrict__ sp,     // [H]
                const float* __restrict__ alphap, // [1]
                const float* __restrict__ rhop,   // [1]
                float* __restrict__ outp)         // [2,B,H] = hy ; cy
{
  // XOR-swizzled 16B-chunk layout: slot (row e, c8) holds global chunk c8^(e&7).
  __shared__ half_t As[BM * BK];    // 16 KB
  __shared__ half_t Bs[BM * BK];    // 16 KB

  const int tid  = threadIdx.x;
  const int w    = tid >> 6;
  const int lane = tid & 63;
  const int l15  = lane & 15;
  const int grp  = lane >> 4;
  const int wr   = w >> 1;
  const int wc   = w & 1;

  // XCD-locality swizzle: wg = 8q+k -> bx = q>>2, by = 4k+(q&3)
  const int wg = blockIdx.x + (blockIdx.y << 5);
  const int xk = wg & 7;
  const int q  = wg >> 3;
  const int m0 = (q >> 2) * BM;
  const int h0 = ((xk << 2) + (q & 3)) * BH;

  f32x4 acc[4][4] = {};              // [m-subtile][gate]

  const int ldr = tid >> 3;          // 0..31
  const int ldc = tid & 7;           // 16B chunk col 0..7

  for (int it = 0; it < NIT; ++it) {
    const bool p1 = it >= INs / BK;
    const half_t* Ap = p1 ? hxp : xin;
    const half_t* Wp = p1 ? whh : wxh;
    const int Ka = p1 ? Hs : INs;
    const int k0 = (p1 ? (it - INs / BK) : it) * BK;
    #pragma unroll
    for (int i = 0; i < 4; ++i) {
      const int e    = i * 32 + ldr;
      const int gc8  = ldc ^ (e & 7);            // swizzle on global side
      const int wrow = ((e >> 4) & 3) * Hs + h0 + ((e >> 6) << 4) + (e & 15);
      const half_t* ga = Ap + (size_t)(m0 + e) * Ka + (k0 + gc8 * 8);
      __builtin_amdgcn_global_load_lds((AS1 void*)ga,
                                       (AS3 void*)(As + (e * 8 + ldc) * 8), 16, 0, 0);
      const half_t* gw = Wp + (size_t)wrow * Ka + (k0 + gc8 * 8);
      __builtin_amdgcn_global_load_lds((AS1 void*)gw,
                                       (AS3 void*)(Bs + (e * 8 + ldc) * 8), 16, 0, 0);
    }
    __syncthreads();

    #pragma unroll
    for (int kk = 0; kk < 2; ++kk) {
      const int c8x = kk * 4 + grp;
      f16x8 af[4], bfr[4];
      #pragma unroll
      for (int mt = 0; mt < 4; ++mt) {
        const int e = wr * 64 + mt * 16 + l15;   // e&7 == l15&7
        af[mt] = *(const f16x8*)(As + (e * 8 + (c8x ^ (l15 & 7))) * 8);
      }
      #pragma unroll
      for (int nt = 0; nt < 4; ++nt) {
        const int e = wc * 64 + nt * 16 + l15;
        bfr[nt] = *(const f16x8*)(Bs + (e * 8 + (c8x ^ (l15 & 7))) * 8);
      }
      #pragma unroll
      for (int mt = 0; mt < 4; ++mt)
        #pragma unroll
        for (int nt = 0; nt < 4; ++nt)
          acc[mt][nt] = __builtin_amdgcn_mfma_f32_16x16x32_f16(
              af[mt], bfr[nt], acc[mt][nt], 0, 0, 0);
    }
    __syncthreads();
  }

  // ---- fused epilogue: each thread owns ONE h and 16 batch rows ----
  const int h = h0 + wc * 16 + l15;
  const float bi  = biasp[h];
  const float bfv = biasp[Hs + h];
  const float bg  = biasp[2 * Hs + h];
  const float bo  = biasp[3 * Hs + h];
  const float sv = sp[h], tauv = taup[h];
  const float alphav = alphap[0], rhov = rhop[0], rh = 0.5f * rhov;
  const float rtau   = 1.0f / tauv;    // hoisted: one divide
  const float tworho = 2.0f / rhov;    // hoisted: one divide

  #pragma unroll
  for (int mt = 0; mt < 4; ++mt) {
    const f32x4 t4 = *(const f32x4*)(timep + m0 + wr * 64 + mt * 16 + grp * 4);
    #pragma unroll
    for (int r = 0; r < 4; ++r) {
      // C/D layout (m89-verified): col = lane&15, row = grp*4 + reg
      const int brow = m0 + wr * 64 + mt * 16 + grp * 4 + r;
      // phi = fmod(tv-s, tau)/tau == q - trunc(q), q = (tv-s)/tau
      const float qv  = (t4[r] - sv) * rtau;
      const float phi = qv - truncf(qv);
      const float kv  = phi < rh   ? phi * tworho
                      : (phi < rhov ? 2.0f - phi * tworho
                                    : alphav * phi);

      const float iv = acc[mt][0][r] + bi;
      const float fv = acc[mt][1][r] + bfv;
      const float gv = acc[mt][2][r] + bg;
      const float ov = acc[mt][3][r] + bo;
      const float cxv = cxp[(size_t)brow * Hs + h];
      const float ft = sigm(fv + 1.0f - kv);
      const float it2 = sigm(iv) * kv;
      const float gt = tanh_fast(gv) * kv;
      const float ot = sigm(ov) * kv;
      const float cy = ft * cxv + it2 * gt;
      const float hy = ot * tanh_fast(cy);

      outp[(size_t)brow * Hs + h] = hy;
      outp[(size_t)Bsz * Hs + (size_t)brow * Hs + h] = cy;
    }
  }
}

// Fallback (no usable ws): single kernel, fp32 converted during staging
// (r0 structure, unchanged).
__global__ __launch_bounds__(256, 3)
void plstm_gemm_f32(const float* __restrict__ xin, const float* __restrict__ timep,
                    const float* __restrict__ hxp, const float* __restrict__ cxp,
                    const float* __restrict__ wxh, const float* __restrict__ biasp,
                    const float* __restrict__ whh, const float* __restrict__ taup,
                    const float* __restrict__ sp, const float* __restrict__ alphap,
                    const float* __restrict__ rhop, float* __restrict__ outp)
{
  __shared__ half_t As[BM * BK];
  __shared__ half_t Bsf[BM * BK];

  const int tid  = threadIdx.x;
  const int w    = tid >> 6;
  const int lane = tid & 63;
  const int l15  = lane & 15;
  const int grp  = lane >> 4;
  const int wr   = w >> 1;
  const int wc   = w & 1;

  const int m0 = blockIdx.x * BM;
  const int h0 = blockIdx.y * BH;

  f32x4 acc[4][4] = {};
  const int ldr = tid >> 3;
  const int ldc = tid & 7;

  for (int it = 0; it < NIT; ++it) {
    const bool p1 = it >= INs / BK;
    const float* Ap = p1 ? hxp : xin;
    const float* Wp = p1 ? whh : wxh;
    const int Ka = p1 ? Hs : INs;
    const int k0 = (p1 ? (it - INs / BK) : it) * BK;
    #pragma unroll
    for (int i = 0; i < 4; ++i) {
      const int e    = i * 32 + ldr;
      const int gc8  = ldc ^ (e & 7);
      const int wrow = ((e >> 4) & 3) * Hs + h0 + ((e >> 6) << 4) + (e & 15);
      const float* ga = Ap + (size_t)(m0 + e) * Ka + (k0 + gc8 * 8);
      const f32x4 a0v = *(const f32x4*)ga, a1v = *(const f32x4*)(ga + 4);
      f16x8 pa;
      pa[0]=(half_t)a0v[0]; pa[1]=(half_t)a0v[1]; pa[2]=(half_t)a0v[2]; pa[3]=(half_t)a0v[3];
      pa[4]=(half_t)a1v[0]; pa[5]=(half_t)a1v[1]; pa[6]=(half_t)a1v[2]; pa[7]=(half_t)a1v[3];
      *(f16x8*)(As + (e * 8 + ldc) * 8) = pa;
      const float* gw = Wp + (size_t)wrow * Ka + (k0 + gc8 * 8);
      const f32x4 b0v = *(const f32x4*)gw, b1v = *(const f32x4*)(gw + 4);
      f16x8 pb;
      pb[0]=(half_t)b0v[0]; pb[1]=(half_t)b0v[1]; pb[2]=(half_t)b0v[2]; pb[3]=(half_t)b0v[3];
      pb[4]=(half_t)b1v[0]; pb[5]=(half_t)b1v[1]; pb[6]=(half_t)b1v[2]; pb[7]=(half_t)b1v[3];
      *(f16x8*)(Bsf + (e * 8 + ldc) * 8) = pb;
    }
    __syncthreads();
    #pragma unroll
    for (int kk = 0; kk < 2; ++kk) {
      const int c8x = kk * 4 + grp;
      f16x8 af[4], bfr[4];
      #pragma unroll
      for (int mt = 0; mt < 4; ++mt) {
        const int e = wr * 64 + mt * 16 + l15;
        af[mt] = *(const f16x8*)(As + (e * 8 + (c8x ^ (l15 & 7))) * 8);
      }
      #pragma unroll
      for (int nt = 0; nt < 4; ++nt) {
        const int e = wc * 64 + nt * 16 + l15;
        bfr[nt] = *(const f16x8*)(Bsf + (e * 8 + (c8x ^ (l15 & 7))) * 8);
      }
      #pragma unroll
      for (int mt = 0; mt < 4; ++mt)
        #pragma unroll
        for (int nt = 0; nt < 4; ++nt)
          acc[mt][nt] = __builtin_amdgcn_mfma_f32_16x16x32_f16(
              af[mt], bfr[nt], acc[mt][nt], 0, 0, 0);
    }
    __syncthreads();
  }

  const int h = h0 + wc * 16 + l15;
  const float bi  = biasp[h];
  const float bfv = biasp[Hs + h];
  const float bg  = biasp[2 * Hs + h];
  const float bo  = biasp[3 * Hs + h];
  const float sv = sp[h], tauv = taup[h];
  const float alphav = alphap[0], rhov = rhop[0], rh = 0.5f * rhov;
  const float rtau   = 1.0f / tauv;
  const float tworho = 2.0f / rhov;

  #pragma unroll
  for (int mt = 0; mt < 4; ++mt) {
    const f32x4 t4 = *(const f32x4*)(timep + m0 + wr * 64 + mt * 16 + grp * 4);
    #pragma unroll
    for (int r = 0; r < 4; ++r) {
      const int brow = m0 + wr * 64 + mt * 16 + grp * 4 + r;
      const float qv  = (t4[r] - sv) * rtau;
      const float phi = qv - truncf(qv);
      const float kv  = phi < rh   ? phi * tworho
                      : (phi < rhov ? 2.0f - phi * tworho
                                    : alphav * phi);
      const float iv = acc[mt][0][r] + bi;
      const float fv = acc[mt][1][r] + bfv;
      const float gv = acc[mt][2][r] + bg;
      const float ov = acc[mt][3][r] + bo;
      const float cxv = cxp[(size_t)brow * Hs + h];
      const float ft = sigm(fv + 1.0f - kv);
      const float it2 = sigm(iv) * kv;
      const float gt = tanh_fast(gv) * kv;
      const float ot = sigm(ov) * kv;
      const float cy = ft * cxv + it2 * gt;
      const float hy = ot * tanh_fast(cy);
      outp[(size_t)brow * Hs + h] = hy;
      outp[(size_t)Bsz * Hs + (size_t)brow * Hs + h] = cy;
    }
  }
}

extern "C" void kernel_launch(void* const* d_in, const int* in_sizes, int n_in,
                              void* d_out, int out_size, void* d_ws, size_t ws_size,
                              hipStream_t stream) {
  (void)in_sizes; (void)n_in; (void)out_size;
  const float* xin   = (const float*)d_in[0];
  const float* timep = (const float*)d_in[1];
  const float* hxp   = (const float*)d_in[2];
  const float* cxp   = (const float*)d_in[3];
  const float* wxh   = (const float*)d_in[4];
  const float* biasp = (const float*)d_in[5];
  const float* whh   = (const float*)d_in[6];
  const float* taup  = (const float*)d_in[7];
  const float* sp    = (const float*)d_in[8];
  const float* alphap= (const float*)d_in[9];
  const float* rhop  = (const float*)d_in[10];
  float* outp = (float*)d_out;

  dim3 grid(Bsz / BM, Hs / BH);   // 32 x 32 = 1024 blocks = 4 per CU
  if (ws_size >= TOT * sizeof(half_t)) {
    half_t* ws = (half_t*)d_ws;
    cvt_kernel<<<(int)(TOT / 8 / 256), 256, 0, stream>>>(xin, hxp, wxh, whh, ws);
    plstm_gemm<<<grid, 256, 0, stream>>>(
        ws + OFF_X, ws + OFF_HX, cxp, ws + OFF_WX, biasp, ws + OFF_WH,
        timep, taup, sp, alphap, rhop, outp);
  } else {
    plstm_gemm_f32<<<grid, 256, 0, stream>>>(
        xin, timep, hxp, cxp, wxh, biasp, whh,
        taup, sp, alphap, rhop, outp);
  }
}